// Round 9
// baseline (23.889 us; speedup 1.0000x reference)
//
#include <hip/hip_runtime.h>
#include <math.h>

// Problem constants (from reference setup_inputs)
#define BS    16
#define NQ    100
#define Q_DIM (BS * NQ)        // 1600
#define T_DIM 320
#define P_DIM 72
#define ROW   (5 + 2 * P_DIM)  // 149 floats per tgt row

#define TT  64                 // t-tile per block
#define QPT 4                  // q per thread (4 waves x 4 = 16 q per block)
#define CHUNK 160              // weights kernel: rows staged per LDS chunk

// ---------------- Kernel 1: weights (runs ONCE, 1 block) ----------------
// Third approach (R2/R6 scatter ~10us; ballot banned after 3 regressions):
// stage tgt rows into LDS via linear float4 copy (the pattern proven fast in
// cost_kernel Phase A), count from LDS. Row stride 149 floats: 149 mod 32 =
// 21, odd -> 64 lanes spread 2/bank = conflict-free.
__global__ __launch_bounds__(256) void weights_kernel(
    const float* __restrict__ tgt,   // [T,149]
    float*       __restrict__ w)     // [T] out
{
    alignas(16) __shared__ float s_rows[CHUNK * ROW];   // 95360 B
    __shared__ float s_vc[T_DIM];
    __shared__ float s_min;
    const int tx = threadIdx.x;

    #pragma unroll
    for (int chunk = 0; chunk < T_DIM / CHUNK; ++chunk) {
        // Linear float4 staging: 160*149 floats = 5960 float4, exactly
        // aligned (chunk offset 95360 B = 5960*16).
        const float4* src4 = reinterpret_cast<const float4*>(tgt + chunk * CHUNK * ROW);
        float4* dst4 = reinterpret_cast<float4*>(s_rows);
        for (int i = tx; i < (CHUNK * ROW) / 4; i += 256) dst4[i] = src4[i];
        __syncthreads();

        if (tx < CHUNK) {
            const float* xs = s_rows + tx * ROW + 5;
            int cnt = 0;
            #pragma unroll 8
            for (int p = 0; p < P_DIM; ++p) cnt += (xs[p] >= 0.0f) ? 1 : 0;
            s_vc[chunk * CHUNK + tx] = (float)cnt;
        }
        __syncthreads();   // protect s_rows before next chunk overwrites
    }

    if (tx < 64) {
        float m = s_vc[tx];
        #pragma unroll
        for (int k = 1; k < T_DIM / 64; ++k) m = fminf(m, s_vc[tx + k * 64]);
        #pragma unroll
        for (int d = 32; d > 0; d >>= 1) m = fminf(m, __shfl_xor(m, d, 64));
        if (tx == 0) s_min = m;
    }
    __syncthreads();

    for (int t = tx; t < T_DIM; t += 256)
        w[t] = sqrtf(s_min / s_vc[t]) * 0.1f;   // includes CURVES_W/10
}

// ---------------- Kernel 2: cost matrix (500 blocks) — unchanged (best: R6/R8) ----------------
__global__ __launch_bounds__(256) void cost_kernel(
    const float* __restrict__ logits,   // [Q,2]
    const float* __restrict__ curves,   // [Q,8]
    const float* __restrict__ tgt,      // [T,149]
    const int*   __restrict__ tgt_ids,  // [T]
    const float* __restrict__ w,        // [T] precomputed wt
    float*       __restrict__ out)      // [Q,T]
{
    alignas(16) __shared__ float s_tgt[TT * ROW];   // 38144 B

    const int tx   = threadIdx.x;
    const int lane = tx & 63;
    const int wave = tx >> 6;               // 0..3
    const int t_base = blockIdx.y * TT;
    const int t = t_base + lane;

    // Issue early (hide under staging): per-lane weight + class id.
    const float wt = w[t];
    const int   id = tgt_ids[t];

    // ---- Phase A: float4 staging (38144 B = 2384 float4, exact) ----
    {
        const float4* src4 = reinterpret_cast<const float4*>(tgt + t_base * ROW);
        float4* dst4 = reinterpret_cast<float4*>(s_tgt);
        #pragma unroll
        for (int i = tx; i < (TT * ROW) / 4; i += 256) dst4[i] = src4[i];
    }
    __syncthreads();

    // ---- Phase D: per-thread constants ----
    const float* srow = s_tgt + lane * ROW;
    const float ly = srow[1], uy = srow[2], lx = srow[3], ux = srow[4];

    const int q0 = blockIdx.x * (4 * QPT) + wave * QPT;   // wave-uniform

    float b0[QPT], b1[QPT], b2[QPT], b3[QPT], base_cost[QPT];
    #pragma unroll
    for (int j = 0; j < QPT; ++j) {
        const int q = q0 + j;
        const float* c = curves + q * 8;   // wave-uniform
        b0[j] = c[0]; b1[j] = c[1]; b2[j] = c[2]; b3[j] = c[3];
        const float b4 = c[4], b5 = c[5], b6 = c[6], b7 = c[7];
        const float l0 = logits[q * 2 + 0], l1 = logits[q * 2 + 1];
        const float m  = fmaxf(l0, l1);
        const float e0 = expf(l0 - m), e1 = expf(l1 - m);
        const float inv = 1.0f / (e0 + e1);
        const float prob = (id == 0) ? e0 * inv : e1 * inv;
        const float cl = (fabsf(b4 - ly) + fabsf(b6 - lx)) * 0.5f;
        const float cu = (fabsf(b5 - uy) + fabsf(b7 - ux)) * 0.5f;
        base_cost[j] = -prob + cl + cu;
    }

    // ---- Phase E: main p-loop ----
    float acc[QPT];
    #pragma unroll
    for (int j = 0; j < QPT; ++j) acc[j] = 0.0f;

    #pragma unroll 8
    for (int p = 0; p < P_DIM; ++p) {
        const float xs = srow[5 + p];              // ds_read2_b32 pair with ys
        const float ys = srow[5 + P_DIM + p];
        const float vmask = (xs >= 0.0f) ? 1.0f : 0.0f;
        #pragma unroll
        for (int j = 0; j < QPT; ++j) {
            const float v = ((b3[j] * ys + b2[j]) * ys + b1[j]) * ys + b0[j];
            acc[j] = fmaf(vmask, fabsf(xs - v), acc[j]);
        }
    }

    #pragma unroll
    for (int j = 0; j < QPT; ++j) {
        const int q = q0 + j;
        out[q * T_DIM + t] = base_cost[j] + acc[j] * wt;
    }
}

extern "C" void kernel_launch(void* const* d_in, const int* in_sizes, int n_in,
                              void* d_out, int out_size, void* d_ws, size_t ws_size,
                              hipStream_t stream) {
    const float* logits  = (const float*)d_in[0];  // [16,100,2]
    const float* curves  = (const float*)d_in[1];  // [16,100,8]
    const float* tgt     = (const float*)d_in[2];  // [320,149]
    const int*   tgt_ids = (const int*)d_in[3];    // [320]
    float* out = (float*)d_out;                    // [16,100,320]
    float* w   = (float*)d_ws;                     // 320 floats scratch

    weights_kernel<<<1, 256, 0, stream>>>(tgt, w);

    dim3 grid(Q_DIM / (4 * QPT), T_DIM / TT);      // (100, 5)
    cost_kernel<<<grid, 256, 0, stream>>>(logits, curves, tgt, tgt_ids, w, out);
}

// Round 10
// 19.033 us; speedup vs baseline: 1.2552x; 1.2552x over previous
//
#include <hip/hip_runtime.h>
#include <math.h>

// Problem constants (from reference setup_inputs)
#define BS    16
#define NQ    100
#define Q_DIM (BS * NQ)        // 1600
#define T_DIM 320
#define P_DIM 72
#define ROW   (5 + 2 * P_DIM)  // 149 floats per tgt row

#define TT  64                 // t-tile per block
#define QPT 4                  // q per thread (4 waves x 4 = 16 q per block)

// ---------------- Kernel 1: weights (runs ONCE, 1 block) ----------------
// Scattered per-thread row counts: each thread's 72 loads are CONTIGUOUS
// within its row (compiler vectorizes to dwordx4) -> ~1us. Empirical record:
//   scatter (R6/R8) 19.0-19.4 | ballot (R7) 22.4 | LDS-staged (R9) 23.9
// Scatter wins every controlled comparison. Do not "fix" this.
__global__ __launch_bounds__(256) void weights_kernel(
    const float* __restrict__ tgt,   // [T,149]
    float*       __restrict__ w)     // [T] out
{
    __shared__ float s_vc[T_DIM];
    __shared__ float s_min;
    const int tx = threadIdx.x;

    for (int t = tx; t < T_DIM; t += 256) {
        const float* xs = tgt + t * ROW + 5;
        int cnt = 0;
        #pragma unroll 8
        for (int p = 0; p < P_DIM; ++p) cnt += (xs[p] >= 0.0f) ? 1 : 0;
        s_vc[t] = (float)cnt;
    }
    __syncthreads();

    if (tx < 64) {
        float m = s_vc[tx];
        #pragma unroll
        for (int k = 1; k < T_DIM / 64; ++k) m = fminf(m, s_vc[tx + k * 64]);
        #pragma unroll
        for (int d = 32; d > 0; d >>= 1) m = fminf(m, __shfl_xor(m, d, 64));
        if (tx == 0) s_min = m;
    }
    __syncthreads();

    for (int t = tx; t < T_DIM; t += 256)
        w[t] = sqrtf(s_min / s_vc[t]) * 0.1f;   // includes CURVES_W/10
}

// ---------------- Kernel 2: cost matrix (500 blocks, 2/CU) ----------------
//  A: float4 staging of this block's 64 tgt rows (coalesced, 16B-aligned)
//  D/E: per-wave-uniform q (scalar curve loads), lane-varying t
//       (LDS stride 149 = odd -> conflict-free), coalesced out writes.
__global__ __launch_bounds__(256) void cost_kernel(
    const float* __restrict__ logits,   // [Q,2]
    const float* __restrict__ curves,   // [Q,8]
    const float* __restrict__ tgt,      // [T,149]
    const int*   __restrict__ tgt_ids,  // [T]
    const float* __restrict__ w,        // [T] precomputed wt
    float*       __restrict__ out)      // [Q,T]
{
    alignas(16) __shared__ float s_tgt[TT * ROW];   // 38144 B

    const int tx   = threadIdx.x;
    const int lane = tx & 63;
    const int wave = tx >> 6;               // 0..3
    const int t_base = blockIdx.y * TT;
    const int t = t_base + lane;

    // Issue early (hide under staging): per-lane weight + class id.
    const float wt = w[t];
    const int   id = tgt_ids[t];

    // ---- Phase A: float4 staging (38144 B = 2384 float4, exact) ----
    {
        const float4* src4 = reinterpret_cast<const float4*>(tgt + t_base * ROW);
        float4* dst4 = reinterpret_cast<float4*>(s_tgt);
        #pragma unroll
        for (int i = tx; i < (TT * ROW) / 4; i += 256) dst4[i] = src4[i];
    }
    __syncthreads();

    // ---- Phase D: per-thread constants ----
    const float* srow = s_tgt + lane * ROW;
    const float ly = srow[1], uy = srow[2], lx = srow[3], ux = srow[4];

    const int q0 = blockIdx.x * (4 * QPT) + wave * QPT;   // wave-uniform

    float b0[QPT], b1[QPT], b2[QPT], b3[QPT], base_cost[QPT];
    #pragma unroll
    for (int j = 0; j < QPT; ++j) {
        const int q = q0 + j;
        const float* c = curves + q * 8;   // wave-uniform
        b0[j] = c[0]; b1[j] = c[1]; b2[j] = c[2]; b3[j] = c[3];
        const float b4 = c[4], b5 = c[5], b6 = c[6], b7 = c[7];
        const float l0 = logits[q * 2 + 0], l1 = logits[q * 2 + 1];
        const float m  = fmaxf(l0, l1);
        const float e0 = expf(l0 - m), e1 = expf(l1 - m);
        const float inv = 1.0f / (e0 + e1);
        const float prob = (id == 0) ? e0 * inv : e1 * inv;
        const float cl = (fabsf(b4 - ly) + fabsf(b6 - lx)) * 0.5f;
        const float cu = (fabsf(b5 - uy) + fabsf(b7 - ux)) * 0.5f;
        base_cost[j] = -prob + cl + cu;
    }

    // ---- Phase E: main p-loop ----
    float acc[QPT];
    #pragma unroll
    for (int j = 0; j < QPT; ++j) acc[j] = 0.0f;

    #pragma unroll 8
    for (int p = 0; p < P_DIM; ++p) {
        const float xs = srow[5 + p];              // ds_read2_b32 pair with ys
        const float ys = srow[5 + P_DIM + p];
        const float vmask = (xs >= 0.0f) ? 1.0f : 0.0f;
        #pragma unroll
        for (int j = 0; j < QPT; ++j) {
            const float v = ((b3[j] * ys + b2[j]) * ys + b1[j]) * ys + b0[j];
            acc[j] = fmaf(vmask, fabsf(xs - v), acc[j]);
        }
    }

    #pragma unroll
    for (int j = 0; j < QPT; ++j) {
        const int q = q0 + j;
        out[q * T_DIM + t] = base_cost[j] + acc[j] * wt;
    }
}

extern "C" void kernel_launch(void* const* d_in, const int* in_sizes, int n_in,
                              void* d_out, int out_size, void* d_ws, size_t ws_size,
                              hipStream_t stream) {
    const float* logits  = (const float*)d_in[0];  // [16,100,2]
    const float* curves  = (const float*)d_in[1];  // [16,100,8]
    const float* tgt     = (const float*)d_in[2];  // [320,149]
    const int*   tgt_ids = (const int*)d_in[3];    // [320]
    float* out = (float*)d_out;                    // [16,100,320]
    float* w   = (float*)d_ws;                     // 320 floats scratch

    weights_kernel<<<1, 256, 0, stream>>>(tgt, w);

    dim3 grid(Q_DIM / (4 * QPT), T_DIM / TT);      // (100, 5)
    cost_kernel<<<grid, 256, 0, stream>>>(logits, curves, tgt, tgt_ids, w, out);
}